// Round 1
// baseline (370.030 us; speedup 1.0000x reference)
//
#include <hip/hip_runtime.h>
#include <math.h>

#define NQ   100000
#define CCH  128
#define HDIM 256
#define WDIM 256
#define HW   (HDIM * WDIM)
#define KPTS 4
#define PDIM 36

// ---------------- transpose (C,H,W) -> (H*W, C), 3 planes ----------------
__global__ void transpose_kernel(const float* __restrict__ f0,
                                 const float* __restrict__ f1,
                                 const float* __restrict__ f2,
                                 float* __restrict__ out) {
  __shared__ float tile[32][33];
  const int plane = blockIdx.z;
  const float* __restrict__ f = (plane == 0) ? f0 : ((plane == 1) ? f1 : f2);
  float* __restrict__ o = out + (size_t)plane * (size_t)HW * CCH;
  const int hw0 = blockIdx.x * 32;
  const int c0 = blockIdx.y * 32;
  const int tx = threadIdx.x;  // 0..31
  const int ty = threadIdx.y;  // 0..7
#pragma unroll
  for (int i = 0; i < 4; ++i) {
    tile[ty + i * 8][tx] = f[(size_t)(c0 + ty + i * 8) * HW + (hw0 + tx)];
  }
  __syncthreads();
#pragma unroll
  for (int i = 0; i < 4; ++i) {
    o[(size_t)(hw0 + ty + i * 8) * CCH + (c0 + tx)] = tile[tx][ty + i * 8];
  }
}

// -------- per-query attn (softmax) + offsets: pe @ Wa/Wo, 3 planes --------
__global__ void weights_kernel(const float* __restrict__ pe,
                               const float* __restrict__ Wa0, const float* __restrict__ ba0,
                               const float* __restrict__ Wo0, const float* __restrict__ bo0,
                               const float* __restrict__ Wa1, const float* __restrict__ ba1,
                               const float* __restrict__ Wo1, const float* __restrict__ bo1,
                               const float* __restrict__ Wa2, const float* __restrict__ ba2,
                               const float* __restrict__ Wo2, const float* __restrict__ bo2,
                               float* __restrict__ attnOut, float* __restrict__ offOut) {
  __shared__ float sWa[3][PDIM][4];   // 432 f
  __shared__ float sWo[3][PDIM][8];   // 864 f
  __shared__ float sba[3][4];
  __shared__ float sbo[3][8];
  const int t = threadIdx.x;
  {
    float* wa = &sWa[0][0][0];
    for (int i = t; i < 144; i += 256) { wa[i] = Wa0[i]; wa[144 + i] = Wa1[i]; wa[288 + i] = Wa2[i]; }
    float* wo = &sWo[0][0][0];
    for (int i = t; i < 288; i += 256) { wo[i] = Wo0[i]; wo[288 + i] = Wo1[i]; wo[576 + i] = Wo2[i]; }
    if (t < 4) { sba[0][t] = ba0[t]; sba[1][t] = ba1[t]; sba[2][t] = ba2[t]; }
    if (t < 8) { sbo[0][t] = bo0[t]; sbo[1][t] = bo1[t]; sbo[2][t] = bo2[t]; }
  }
  __syncthreads();

  const int n = blockIdx.x * 256 + t;
  if (n >= NQ) return;

  float p[PDIM];
  const float4* pe4 = (const float4*)(pe + (size_t)n * PDIM);
#pragma unroll
  for (int i = 0; i < 9; ++i) {
    float4 v = pe4[i];
    p[4 * i + 0] = v.x; p[4 * i + 1] = v.y; p[4 * i + 2] = v.z; p[4 * i + 3] = v.w;
  }

  float la[3][4], of[3][8];
#pragma unroll
  for (int pl = 0; pl < 3; ++pl) {
#pragma unroll
    for (int k = 0; k < 4; ++k) la[pl][k] = sba[pl][k];
#pragma unroll
    for (int d = 0; d < 8; ++d) of[pl][d] = sbo[pl][d];
  }
#pragma unroll 4
  for (int j = 0; j < PDIM; ++j) {
    const float pj = p[j];
#pragma unroll
    for (int pl = 0; pl < 3; ++pl) {
#pragma unroll
      for (int k = 0; k < 4; ++k) la[pl][k] = fmaf(pj, sWa[pl][j][k], la[pl][k]);
#pragma unroll
      for (int d = 0; d < 8; ++d) of[pl][d] = fmaf(pj, sWo[pl][j][d], of[pl][d]);
    }
  }

  float* aB = attnOut + (size_t)n * 12;
  float* oB = offOut + (size_t)n * 24;
#pragma unroll
  for (int pl = 0; pl < 3; ++pl) {
    const float m = fmaxf(fmaxf(la[pl][0], la[pl][1]), fmaxf(la[pl][2], la[pl][3]));
    const float e0 = expf(la[pl][0] - m);
    const float e1 = expf(la[pl][1] - m);
    const float e2 = expf(la[pl][2] - m);
    const float e3 = expf(la[pl][3] - m);
    const float inv = 1.0f / (e0 + e1 + e2 + e3);
    aB[pl * 4 + 0] = e0 * inv;
    aB[pl * 4 + 1] = e1 * inv;
    aB[pl * 4 + 2] = e2 * inv;
    aB[pl * 4 + 3] = e3 * inv;
#pragma unroll
    for (int d = 0; d < 8; ++d) oB[pl * 8 + d] = of[pl][d];
  }
}

// -------- main gather: 1 wave per query, lane = channel pair (float2) --------
__global__ void sample_kernel(const float* __restrict__ query,
                              const float* __restrict__ featT,
                              const float* __restrict__ attnB,
                              const float* __restrict__ offB,
                              float* __restrict__ out) {
  const int lane = threadIdx.x & 63;
  const int wid = threadIdx.x >> 6;
  int q = blockIdx.x * 4 + wid;
  q = __builtin_amdgcn_readfirstlane(q);
  if (q >= NQ) return;

  const float qx = query[q * 3 + 0];
  const float qy = query[q * 3 + 1];
  const float qz = query[q * 3 + 2];

  float at[12], of[24];
  const float* __restrict__ aB = attnB + (size_t)q * 12;
  const float* __restrict__ oB = offB + (size_t)q * 24;
#pragma unroll
  for (int i = 0; i < 12; ++i) at[i] = aB[i];
#pragma unroll
  for (int i = 0; i < 24; ++i) of[i] = oB[i];

  float accx = 0.0f, accy = 0.0f;
#pragma unroll
  for (int pl = 0; pl < 3; ++pl) {
    // coords pair per plane: xy:(q0,q1) xz:(q0,q2) yz:(q1,q2)
    const float ca = (pl == 2) ? qy : qx;   // coords[...,0] -> gy
    const float cb = (pl == 0) ? qy : qz;   // coords[...,1] -> gx
    const float* __restrict__ f = featT + (size_t)pl * (size_t)HW * CCH + lane * 2;
#pragma unroll
    for (int k = 0; k < KPTS; ++k) {
      const float gy = ca + of[pl * 8 + k * 2 + 0];
      const float gx = cb + of[pl * 8 + k * 2 + 1];
      float x = ((gx + 1.0f) * (float)WDIM - 1.0f) * 0.5f;
      float y = ((gy + 1.0f) * (float)HDIM - 1.0f) * 0.5f;
      x = fminf(fmaxf(x, 0.0f), (float)(WDIM - 1));
      y = fminf(fmaxf(y, 0.0f), (float)(HDIM - 1));
      const float x0f = floorf(x), y0f = floorf(y);
      const float wx = x - x0f, wy = y - y0f;
      const int xi0 = (int)x0f, yi0 = (int)y0f;
      const int xi1 = min(xi0 + 1, WDIM - 1);
      const int yi1 = min(yi0 + 1, HDIM - 1);
      const float a = at[pl * 4 + k];
      const float w00 = a * (1.0f - wx) * (1.0f - wy);
      const float w01 = a * wx * (1.0f - wy);
      const float w10 = a * (1.0f - wx) * wy;
      const float w11 = a * wx * wy;
      const int r0 = (yi0 * WDIM) * CCH;
      const int r1 = (yi1 * WDIM) * CCH;
      const float2 v00 = *(const float2*)(f + r0 + xi0 * CCH);
      const float2 v01 = *(const float2*)(f + r0 + xi1 * CCH);
      const float2 v10 = *(const float2*)(f + r1 + xi0 * CCH);
      const float2 v11 = *(const float2*)(f + r1 + xi1 * CCH);
      accx += w00 * v00.x + w01 * v01.x + w10 * v10.x + w11 * v11.x;
      accy += w00 * v00.y + w01 * v01.y + w10 * v10.y + w11 * v11.y;
    }
  }
  *(float2*)(out + (size_t)q * CCH + lane * 2) = make_float2(accx, accy);
}

// -------- fallback: fused, direct (C,H,W) gather (used only if ws too small) --------
__global__ void fused_fallback(const float* __restrict__ query,
                               const float* __restrict__ pe,
                               const float* __restrict__ f0,
                               const float* __restrict__ f1,
                               const float* __restrict__ f2,
                               const float* __restrict__ Wa0, const float* __restrict__ ba0,
                               const float* __restrict__ Wo0, const float* __restrict__ bo0,
                               const float* __restrict__ Wa1, const float* __restrict__ ba1,
                               const float* __restrict__ Wo1, const float* __restrict__ bo1,
                               const float* __restrict__ Wa2, const float* __restrict__ ba2,
                               const float* __restrict__ Wo2, const float* __restrict__ bo2,
                               float* __restrict__ out) {
  const int lane = threadIdx.x & 63;
  const int wid = threadIdx.x >> 6;
  int q = blockIdx.x * 4 + wid;
  q = __builtin_amdgcn_readfirstlane(q);
  if (q >= NQ) return;
  const float qx = query[q * 3 + 0];
  const float qy = query[q * 3 + 1];
  const float qz = query[q * 3 + 2];
  const float* pep = pe + (size_t)q * PDIM;
  const int c0i = lane * 2, c1i = lane * 2 + 1;
  float accx = 0.0f, accy = 0.0f;
#pragma unroll
  for (int pl = 0; pl < 3; ++pl) {
    const float* Wa = (pl == 0) ? Wa0 : ((pl == 1) ? Wa1 : Wa2);
    const float* ba = (pl == 0) ? ba0 : ((pl == 1) ? ba1 : ba2);
    const float* Wo = (pl == 0) ? Wo0 : ((pl == 1) ? Wo1 : Wo2);
    const float* bo = (pl == 0) ? bo0 : ((pl == 1) ? bo1 : bo2);
    const float* f = (pl == 0) ? f0 : ((pl == 1) ? f1 : f2);
    float la[4] = {ba[0], ba[1], ba[2], ba[3]};
    float of[8];
    for (int d = 0; d < 8; ++d) of[d] = bo[d];
    for (int j = 0; j < PDIM; ++j) {
      const float pj = pep[j];
      for (int k = 0; k < 4; ++k) la[k] = fmaf(pj, Wa[j * 4 + k], la[k]);
      for (int d = 0; d < 8; ++d) of[d] = fmaf(pj, Wo[j * 8 + d], of[d]);
    }
    const float m = fmaxf(fmaxf(la[0], la[1]), fmaxf(la[2], la[3]));
    float e[4], s = 0.0f;
    for (int k = 0; k < 4; ++k) { e[k] = expf(la[k] - m); s += e[k]; }
    const float inv = 1.0f / s;
    const float ca = (pl == 2) ? qy : qx;
    const float cb = (pl == 0) ? qy : qz;
    for (int k = 0; k < 4; ++k) {
      const float gy = ca + of[k * 2 + 0];
      const float gx = cb + of[k * 2 + 1];
      float x = ((gx + 1.0f) * (float)WDIM - 1.0f) * 0.5f;
      float y = ((gy + 1.0f) * (float)HDIM - 1.0f) * 0.5f;
      x = fminf(fmaxf(x, 0.0f), (float)(WDIM - 1));
      y = fminf(fmaxf(y, 0.0f), (float)(HDIM - 1));
      const float x0f = floorf(x), y0f = floorf(y);
      const float wx = x - x0f, wy = y - y0f;
      const int xi0 = (int)x0f, yi0 = (int)y0f;
      const int xi1 = min(xi0 + 1, WDIM - 1);
      const int yi1 = min(yi0 + 1, HDIM - 1);
      const float a = e[k] * inv;
      const float w00 = a * (1.0f - wx) * (1.0f - wy);
      const float w01 = a * wx * (1.0f - wy);
      const float w10 = a * (1.0f - wx) * wy;
      const float w11 = a * wx * wy;
      const size_t p00 = (size_t)(yi0 * WDIM + xi0);
      const size_t p01 = (size_t)(yi0 * WDIM + xi1);
      const size_t p10 = (size_t)(yi1 * WDIM + xi0);
      const size_t p11 = (size_t)(yi1 * WDIM + xi1);
      const float* fa = f + (size_t)c0i * HW;
      const float* fb = f + (size_t)c1i * HW;
      accx += w00 * fa[p00] + w01 * fa[p01] + w10 * fa[p10] + w11 * fa[p11];
      accy += w00 * fb[p00] + w01 * fb[p01] + w10 * fb[p10] + w11 * fb[p11];
    }
  }
  *(float2*)(out + (size_t)q * CCH + lane * 2) = make_float2(accx, accy);
}

extern "C" void kernel_launch(void* const* d_in, const int* in_sizes, int n_in,
                              void* d_out, int out_size, void* d_ws, size_t ws_size,
                              hipStream_t stream) {
  const float* query = (const float*)d_in[0];
  const float* pe    = (const float*)d_in[1];
  const float* feat0 = (const float*)d_in[2];
  const float* Wa0   = (const float*)d_in[3];
  const float* ba0   = (const float*)d_in[4];
  const float* Wo0   = (const float*)d_in[5];
  const float* bo0   = (const float*)d_in[6];
  const float* feat1 = (const float*)d_in[7];
  const float* Wa1   = (const float*)d_in[8];
  const float* ba1   = (const float*)d_in[9];
  const float* Wo1   = (const float*)d_in[10];
  const float* bo1   = (const float*)d_in[11];
  const float* feat2 = (const float*)d_in[12];
  const float* Wa2   = (const float*)d_in[13];
  const float* ba2   = (const float*)d_in[14];
  const float* Wo2   = (const float*)d_in[15];
  const float* bo2   = (const float*)d_in[16];
  float* out = (float*)d_out;

  const size_t featT_elems = 3ull * HW * CCH;                 // 25,165,824 f
  const size_t need = (featT_elems + (size_t)NQ * 36) * sizeof(float);  // ~115 MB

  if (ws_size >= need) {
    float* featT = (float*)d_ws;
    float* attnB = featT + featT_elems;
    float* offB  = attnB + (size_t)NQ * 12;
    transpose_kernel<<<dim3(HW / 32, CCH / 32, 3), dim3(32, 8), 0, stream>>>(
        feat0, feat1, feat2, featT);
    weights_kernel<<<dim3((NQ + 255) / 256), dim3(256), 0, stream>>>(
        pe, Wa0, ba0, Wo0, bo0, Wa1, ba1, Wo1, bo1, Wa2, ba2, Wo2, bo2, attnB, offB);
    sample_kernel<<<dim3((NQ + 3) / 4), dim3(256), 0, stream>>>(
        query, featT, attnB, offB, out);
  } else {
    fused_fallback<<<dim3((NQ + 3) / 4), dim3(256), 0, stream>>>(
        query, pe, feat0, feat1, feat2,
        Wa0, ba0, Wo0, bo0, Wa1, ba1, Wo1, bo1, Wa2, ba2, Wo2, bo2, out);
  }
}

// Round 2
// 206.738 us; speedup vs baseline: 1.7899x; 1.7899x over previous
//
#include <hip/hip_runtime.h>
#include <math.h>

#define NQ   100000
#define CCH  128
#define HDIM 256
#define WDIM 256
#define HW   (HDIM * WDIM)
#define KPTS 4
#define PDIM 36

// round-to-nearest-even fp32 -> bf16 bits
__device__ inline unsigned int f2bf(float x) {
  unsigned int u = __float_as_uint(x);
  return (u + 0x7fffu + ((u >> 16) & 1u)) >> 16;
}

// ---- transpose + downconvert: (C,H,W) fp32 -> (H*W, C/2) packed 2xbf16 ----
__global__ void transpose_kernel(const float* __restrict__ f0,
                                 const float* __restrict__ f1,
                                 const float* __restrict__ f2,
                                 unsigned int* __restrict__ out) {
  __shared__ float tile[64][65];  // [c_local][hw_local]
  const int plane = blockIdx.z;
  const float* __restrict__ f = (plane == 0) ? f0 : ((plane == 1) ? f1 : f2);
  unsigned int* __restrict__ o = out + (size_t)plane * (size_t)HW * (CCH / 2);
  const int hw0 = blockIdx.x * 64;
  const int c0 = blockIdx.y * 64;
  const int t = threadIdx.x;  // 0..255
  const int c_l = t >> 6;     // 0..3
  const int hw_l = t & 63;    // 0..63
#pragma unroll
  for (int i = 0; i < 16; ++i) {
    tile[c_l + 4 * i][hw_l] = f[(size_t)(c0 + c_l + 4 * i) * HW + (hw0 + hw_l)];
  }
  __syncthreads();
#pragma unroll
  for (int i = 0; i < 8; ++i) {
    const int idx = t + 256 * i;
    const int j = idx & 31;   // channel-pair within tile
    const int r = idx >> 5;   // hw row within tile (0..63)
    const unsigned int lo = f2bf(tile[2 * j][r]);
    const unsigned int hi = f2bf(tile[2 * j + 1][r]);
    o[(size_t)(hw0 + r) * (CCH / 2) + (c0 / 2 + j)] = (hi << 16) | lo;
  }
}

// -------- per-query attn (softmax) + offsets: pe @ Wa/Wo, 3 planes --------
__global__ void weights_kernel(const float* __restrict__ pe,
                               const float* __restrict__ Wa0, const float* __restrict__ ba0,
                               const float* __restrict__ Wo0, const float* __restrict__ bo0,
                               const float* __restrict__ Wa1, const float* __restrict__ ba1,
                               const float* __restrict__ Wo1, const float* __restrict__ bo1,
                               const float* __restrict__ Wa2, const float* __restrict__ ba2,
                               const float* __restrict__ Wo2, const float* __restrict__ bo2,
                               float* __restrict__ attnOut, float* __restrict__ offOut) {
  __shared__ float sWa[3][PDIM][4];
  __shared__ float sWo[3][PDIM][8];
  __shared__ float sba[3][4];
  __shared__ float sbo[3][8];
  const int t = threadIdx.x;
  {
    float* wa = &sWa[0][0][0];
    for (int i = t; i < 144; i += 256) { wa[i] = Wa0[i]; wa[144 + i] = Wa1[i]; wa[288 + i] = Wa2[i]; }
    float* wo = &sWo[0][0][0];
    for (int i = t; i < 288; i += 256) { wo[i] = Wo0[i]; wo[288 + i] = Wo1[i]; wo[576 + i] = Wo2[i]; }
    if (t < 4) { sba[0][t] = ba0[t]; sba[1][t] = ba1[t]; sba[2][t] = ba2[t]; }
    if (t < 8) { sbo[0][t] = bo0[t]; sbo[1][t] = bo1[t]; sbo[2][t] = bo2[t]; }
  }
  __syncthreads();

  const int n = blockIdx.x * 256 + t;
  if (n >= NQ) return;

  float p[PDIM];
  const float4* pe4 = (const float4*)(pe + (size_t)n * PDIM);
#pragma unroll
  for (int i = 0; i < 9; ++i) {
    float4 v = pe4[i];
    p[4 * i + 0] = v.x; p[4 * i + 1] = v.y; p[4 * i + 2] = v.z; p[4 * i + 3] = v.w;
  }

  float la[3][4], of[3][8];
#pragma unroll
  for (int pl = 0; pl < 3; ++pl) {
#pragma unroll
    for (int k = 0; k < 4; ++k) la[pl][k] = sba[pl][k];
#pragma unroll
    for (int d = 0; d < 8; ++d) of[pl][d] = sbo[pl][d];
  }
#pragma unroll 4
  for (int j = 0; j < PDIM; ++j) {
    const float pj = p[j];
#pragma unroll
    for (int pl = 0; pl < 3; ++pl) {
#pragma unroll
      for (int k = 0; k < 4; ++k) la[pl][k] = fmaf(pj, sWa[pl][j][k], la[pl][k]);
#pragma unroll
      for (int d = 0; d < 8; ++d) of[pl][d] = fmaf(pj, sWo[pl][j][d], of[pl][d]);
    }
  }

  float* aB = attnOut + (size_t)n * 12;
  float* oB = offOut + (size_t)n * 24;
#pragma unroll
  for (int pl = 0; pl < 3; ++pl) {
    const float m = fmaxf(fmaxf(la[pl][0], la[pl][1]), fmaxf(la[pl][2], la[pl][3]));
    const float e0 = expf(la[pl][0] - m);
    const float e1 = expf(la[pl][1] - m);
    const float e2 = expf(la[pl][2] - m);
    const float e3 = expf(la[pl][3] - m);
    const float inv = 1.0f / (e0 + e1 + e2 + e3);
    aB[pl * 4 + 0] = e0 * inv;
    aB[pl * 4 + 1] = e1 * inv;
    aB[pl * 4 + 2] = e2 * inv;
    aB[pl * 4 + 3] = e3 * inv;
#pragma unroll
    for (int d = 0; d < 8; ++d) oB[pl * 8 + d] = of[pl][d];
  }
}

// ---- main gather: 1 wave per query, lane = channel pair (packed 2xbf16) ----
__global__ void sample_kernel(const float* __restrict__ query,
                              const unsigned int* __restrict__ featT,
                              const float* __restrict__ attnB,
                              const float* __restrict__ offB,
                              float* __restrict__ out) {
  const int lane = threadIdx.x & 63;
  const int wid = threadIdx.x >> 6;
  int q = blockIdx.x * 4 + wid;
  q = __builtin_amdgcn_readfirstlane(q);
  if (q >= NQ) return;

  const float qx = query[q * 3 + 0];
  const float qy = query[q * 3 + 1];
  const float qz = query[q * 3 + 2];

  float at[12], of[24];
  const float* __restrict__ aB = attnB + (size_t)q * 12;
  const float* __restrict__ oB = offB + (size_t)q * 24;
#pragma unroll
  for (int i = 0; i < 12; ++i) at[i] = aB[i];
#pragma unroll
  for (int i = 0; i < 24; ++i) of[i] = oB[i];

  float accx = 0.0f, accy = 0.0f;
#pragma unroll
  for (int pl = 0; pl < 3; ++pl) {
    // coords pair per plane: xy:(q0,q1) xz:(q0,q2) yz:(q1,q2)
    const float ca = (pl == 2) ? qy : qx;   // coords[...,0] -> gy
    const float cb = (pl == 0) ? qy : qz;   // coords[...,1] -> gx
    const unsigned int* __restrict__ f =
        featT + (size_t)pl * (size_t)HW * (CCH / 2) + lane;
#pragma unroll
    for (int k = 0; k < KPTS; ++k) {
      const float gy = ca + of[pl * 8 + k * 2 + 0];
      const float gx = cb + of[pl * 8 + k * 2 + 1];
      float x = ((gx + 1.0f) * (float)WDIM - 1.0f) * 0.5f;
      float y = ((gy + 1.0f) * (float)HDIM - 1.0f) * 0.5f;
      x = fminf(fmaxf(x, 0.0f), (float)(WDIM - 1));
      y = fminf(fmaxf(y, 0.0f), (float)(HDIM - 1));
      const float x0f = floorf(x), y0f = floorf(y);
      const float wx = x - x0f, wy = y - y0f;
      const int xi0 = (int)x0f, yi0 = (int)y0f;
      const int xi1 = min(xi0 + 1, WDIM - 1);
      const int yi1 = min(yi0 + 1, HDIM - 1);
      const float a = at[pl * 4 + k];
      const float w00 = a * (1.0f - wx) * (1.0f - wy);
      const float w01 = a * wx * (1.0f - wy);
      const float w10 = a * (1.0f - wx) * wy;
      const float w11 = a * wx * wy;
      const int r0 = (yi0 * WDIM) * (CCH / 2);
      const int r1 = (yi1 * WDIM) * (CCH / 2);
      const unsigned int u00 = f[r0 + xi0 * (CCH / 2)];
      const unsigned int u01 = f[r0 + xi1 * (CCH / 2)];
      const unsigned int u10 = f[r1 + xi0 * (CCH / 2)];
      const unsigned int u11 = f[r1 + xi1 * (CCH / 2)];
      // low 16 bits = even channel, high 16 bits = odd channel
      accx += w00 * __uint_as_float(u00 << 16) + w01 * __uint_as_float(u01 << 16) +
              w10 * __uint_as_float(u10 << 16) + w11 * __uint_as_float(u11 << 16);
      accy += w00 * __uint_as_float(u00 & 0xffff0000u) + w01 * __uint_as_float(u01 & 0xffff0000u) +
              w10 * __uint_as_float(u10 & 0xffff0000u) + w11 * __uint_as_float(u11 & 0xffff0000u);
    }
  }
  *(float2*)(out + (size_t)q * CCH + lane * 2) = make_float2(accx, accy);
}

// -------- fallback: fused, direct (C,H,W) gather (used only if ws too small) --------
__global__ void fused_fallback(const float* __restrict__ query,
                               const float* __restrict__ pe,
                               const float* __restrict__ f0,
                               const float* __restrict__ f1,
                               const float* __restrict__ f2,
                               const float* __restrict__ Wa0, const float* __restrict__ ba0,
                               const float* __restrict__ Wo0, const float* __restrict__ bo0,
                               const float* __restrict__ Wa1, const float* __restrict__ ba1,
                               const float* __restrict__ Wo1, const float* __restrict__ bo1,
                               const float* __restrict__ Wa2, const float* __restrict__ ba2,
                               const float* __restrict__ Wo2, const float* __restrict__ bo2,
                               float* __restrict__ out) {
  const int lane = threadIdx.x & 63;
  const int wid = threadIdx.x >> 6;
  int q = blockIdx.x * 4 + wid;
  q = __builtin_amdgcn_readfirstlane(q);
  if (q >= NQ) return;
  const float qx = query[q * 3 + 0];
  const float qy = query[q * 3 + 1];
  const float qz = query[q * 3 + 2];
  const float* pep = pe + (size_t)q * PDIM;
  const int c0i = lane * 2, c1i = lane * 2 + 1;
  float accx = 0.0f, accy = 0.0f;
#pragma unroll
  for (int pl = 0; pl < 3; ++pl) {
    const float* Wa = (pl == 0) ? Wa0 : ((pl == 1) ? Wa1 : Wa2);
    const float* ba = (pl == 0) ? ba0 : ((pl == 1) ? ba1 : ba2);
    const float* Wo = (pl == 0) ? Wo0 : ((pl == 1) ? Wo1 : Wo2);
    const float* bo = (pl == 0) ? bo0 : ((pl == 1) ? bo1 : bo2);
    const float* f = (pl == 0) ? f0 : ((pl == 1) ? f1 : f2);
    float la[4] = {ba[0], ba[1], ba[2], ba[3]};
    float of[8];
    for (int d = 0; d < 8; ++d) of[d] = bo[d];
    for (int j = 0; j < PDIM; ++j) {
      const float pj = pep[j];
      for (int k = 0; k < 4; ++k) la[k] = fmaf(pj, Wa[j * 4 + k], la[k]);
      for (int d = 0; d < 8; ++d) of[d] = fmaf(pj, Wo[j * 8 + d], of[d]);
    }
    const float m = fmaxf(fmaxf(la[0], la[1]), fmaxf(la[2], la[3]));
    float e[4], s = 0.0f;
    for (int k = 0; k < 4; ++k) { e[k] = expf(la[k] - m); s += e[k]; }
    const float inv = 1.0f / s;
    const float ca = (pl == 2) ? qy : qx;
    const float cb = (pl == 0) ? qy : qz;
    for (int k = 0; k < 4; ++k) {
      const float gy = ca + of[k * 2 + 0];
      const float gx = cb + of[k * 2 + 1];
      float x = ((gx + 1.0f) * (float)WDIM - 1.0f) * 0.5f;
      float y = ((gy + 1.0f) * (float)HDIM - 1.0f) * 0.5f;
      x = fminf(fmaxf(x, 0.0f), (float)(WDIM - 1));
      y = fminf(fmaxf(y, 0.0f), (float)(HDIM - 1));
      const float x0f = floorf(x), y0f = floorf(y);
      const float wx = x - x0f, wy = y - y0f;
      const int xi0 = (int)x0f, yi0 = (int)y0f;
      const int xi1 = min(xi0 + 1, WDIM - 1);
      const int yi1 = min(yi0 + 1, HDIM - 1);
      const float a = e[k] * inv;
      const float w00 = a * (1.0f - wx) * (1.0f - wy);
      const float w01 = a * wx * (1.0f - wy);
      const float w10 = a * (1.0f - wx) * wy;
      const float w11 = a * wx * wy;
      const size_t p00 = (size_t)(yi0 * WDIM + xi0);
      const size_t p01 = (size_t)(yi0 * WDIM + xi1);
      const size_t p10 = (size_t)(yi1 * WDIM + xi0);
      const size_t p11 = (size_t)(yi1 * WDIM + xi1);
      const float* fa = f + (size_t)c0i * HW;
      const float* fb = f + (size_t)c1i * HW;
      accx += w00 * fa[p00] + w01 * fa[p01] + w10 * fa[p10] + w11 * fa[p11];
      accy += w00 * fb[p00] + w01 * fb[p01] + w10 * fb[p10] + w11 * fb[p11];
    }
  }
  *(float2*)(out + (size_t)q * CCH + lane * 2) = make_float2(accx, accy);
}

extern "C" void kernel_launch(void* const* d_in, const int* in_sizes, int n_in,
                              void* d_out, int out_size, void* d_ws, size_t ws_size,
                              hipStream_t stream) {
  const float* query = (const float*)d_in[0];
  const float* pe    = (const float*)d_in[1];
  const float* feat0 = (const float*)d_in[2];
  const float* Wa0   = (const float*)d_in[3];
  const float* ba0   = (const float*)d_in[4];
  const float* Wo0   = (const float*)d_in[5];
  const float* bo0   = (const float*)d_in[6];
  const float* feat1 = (const float*)d_in[7];
  const float* Wa1   = (const float*)d_in[8];
  const float* ba1   = (const float*)d_in[9];
  const float* Wo1   = (const float*)d_in[10];
  const float* bo1   = (const float*)d_in[11];
  const float* feat2 = (const float*)d_in[12];
  const float* Wa2   = (const float*)d_in[13];
  const float* ba2   = (const float*)d_in[14];
  const float* Wo2   = (const float*)d_in[15];
  const float* bo2   = (const float*)d_in[16];
  float* out = (float*)d_out;

  const size_t featT_elems = 3ull * HW * (CCH / 2);            // uint32 count
  const size_t need = featT_elems * 4 + (size_t)NQ * 36 * 4;   // ~65 MB

  if (ws_size >= need) {
    unsigned int* featT = (unsigned int*)d_ws;
    float* attnB = (float*)(featT + featT_elems);
    float* offB  = attnB + (size_t)NQ * 12;
    transpose_kernel<<<dim3(HW / 64, CCH / 64, 3), dim3(256), 0, stream>>>(
        feat0, feat1, feat2, featT);
    weights_kernel<<<dim3((NQ + 255) / 256), dim3(256), 0, stream>>>(
        pe, Wa0, ba0, Wo0, bo0, Wa1, ba1, Wo1, bo1, Wa2, ba2, Wo2, bo2, attnB, offB);
    sample_kernel<<<dim3((NQ + 3) / 4), dim3(256), 0, stream>>>(
        query, featT, attnB, offB, out);
  } else {
    fused_fallback<<<dim3((NQ + 3) / 4), dim3(256), 0, stream>>>(
        query, pe, feat0, feat1, feat2,
        Wa0, ba0, Wo0, bo0, Wa1, ba1, Wo1, bo1, Wa2, ba2, Wo2, bo2, out);
  }
}

// Round 3
// 155.154 us; speedup vs baseline: 2.3849x; 1.3325x over previous
//
#include <hip/hip_runtime.h>
#include <math.h>

#define NQ   100000
#define CCH  128
#define HDIM 256
#define WDIM 256
#define HW   (HDIM * WDIM)
#define KPTS 4
#define PDIM 36
#define NBIN 4096   // 16x16x16 Morton bins
#define RECW 40     // floats per sorted-query record

// round-to-nearest-even fp32 -> bf16 bits
__device__ inline unsigned int f2bf(float x) {
  unsigned int u = __float_as_uint(x);
  return (u + 0x7fffu + ((u >> 16) & 1u)) >> 16;
}

__device__ inline int axis_bin(float x) {
  int b = (int)((x + 1.0f) * 8.0f);
  return min(15, max(0, b));
}
__device__ inline unsigned int spread4(unsigned int x) {
  return (x & 1u) | ((x & 2u) << 2) | ((x & 4u) << 4) | ((x & 8u) << 6);
}
__device__ inline unsigned int bin_of(float x, float y, float z) {
  return spread4((unsigned int)axis_bin(x)) |
         (spread4((unsigned int)axis_bin(y)) << 1) |
         (spread4((unsigned int)axis_bin(z)) << 2);
}

// ---- transpose + downconvert: (C,H,W) fp32 -> (H*W, C/2) packed 2xbf16 ----
__global__ void transpose_kernel(const float* __restrict__ f0,
                                 const float* __restrict__ f1,
                                 const float* __restrict__ f2,
                                 unsigned int* __restrict__ out) {
  __shared__ float tile[64][65];  // [c_local][hw_local]
  const int plane = blockIdx.z;
  const float* __restrict__ f = (plane == 0) ? f0 : ((plane == 1) ? f1 : f2);
  unsigned int* __restrict__ o = out + (size_t)plane * (size_t)HW * (CCH / 2);
  const int hw0 = blockIdx.x * 64;
  const int c0 = blockIdx.y * 64;
  const int t = threadIdx.x;  // 0..255
  const int c_l = t >> 6;     // 0..3
  const int hw_l = t & 63;    // 0..63
#pragma unroll
  for (int i = 0; i < 16; ++i) {
    tile[c_l + 4 * i][hw_l] = f[(size_t)(c0 + c_l + 4 * i) * HW + (hw0 + hw_l)];
  }
  __syncthreads();
#pragma unroll
  for (int i = 0; i < 8; ++i) {
    const int idx = t + 256 * i;
    const int j = idx & 31;   // channel-pair within tile
    const int r = idx >> 5;   // hw row within tile (0..63)
    const unsigned int lo = f2bf(tile[2 * j][r]);
    const unsigned int hi = f2bf(tile[2 * j + 1][r]);
    o[(size_t)(hw0 + r) * (CCH / 2) + (c0 / 2 + j)] = (hi << 16) | lo;
  }
}

// ---------------- sort pipeline ----------------
__global__ void zero_kernel(unsigned int* __restrict__ counts) {
  const int t = blockIdx.x * 256 + threadIdx.x;
  if (t < NBIN) counts[t] = 0;
}

__global__ void hist_kernel(const float* __restrict__ query,
                            unsigned int* __restrict__ counts) {
  const int q = blockIdx.x * 256 + threadIdx.x;
  if (q >= NQ) return;
  const unsigned int b = bin_of(query[q * 3 + 0], query[q * 3 + 1], query[q * 3 + 2]);
  atomicAdd(&counts[b], 1u);
}

__global__ void scan_kernel(const unsigned int* __restrict__ counts,
                            unsigned int* __restrict__ offs) {
  __shared__ unsigned int s[1024];
  const int t = threadIdx.x;
  const unsigned int c0 = counts[4 * t + 0];
  const unsigned int c1 = counts[4 * t + 1];
  const unsigned int c2 = counts[4 * t + 2];
  const unsigned int c3 = counts[4 * t + 3];
  const unsigned int sum = c0 + c1 + c2 + c3;
  s[t] = sum;
  __syncthreads();
  for (int d = 1; d < 1024; d <<= 1) {
    const unsigned int v = (t >= d) ? s[t - d] : 0u;
    __syncthreads();
    s[t] += v;
    __syncthreads();
  }
  const unsigned int base = s[t] - sum;  // exclusive prefix
  offs[4 * t + 0] = base;
  offs[4 * t + 1] = base + c0;
  offs[4 * t + 2] = base + c0 + c1;
  offs[4 * t + 3] = base + c0 + c1 + c2;
}

__global__ void scatter_kernel(const float* __restrict__ query,
                               unsigned int* __restrict__ offs,
                               unsigned int* __restrict__ perm) {
  const int q = blockIdx.x * 256 + threadIdx.x;
  if (q >= NQ) return;
  const unsigned int b = bin_of(query[q * 3 + 0], query[q * 3 + 1], query[q * 3 + 2]);
  const unsigned int pos = atomicAdd(&offs[b], 1u);
  perm[pos] = (unsigned int)q;
}

// -- per-sorted-query record: query xyz + softmax(attn) + offsets, 3 planes --
__global__ void weights_kernel(const float* __restrict__ query,
                               const float* __restrict__ pe,
                               const unsigned int* __restrict__ perm,
                               const float* __restrict__ Wa0, const float* __restrict__ ba0,
                               const float* __restrict__ Wo0, const float* __restrict__ bo0,
                               const float* __restrict__ Wa1, const float* __restrict__ ba1,
                               const float* __restrict__ Wo1, const float* __restrict__ bo1,
                               const float* __restrict__ Wa2, const float* __restrict__ ba2,
                               const float* __restrict__ Wo2, const float* __restrict__ bo2,
                               float* __restrict__ rec) {
  __shared__ float sWa[3][PDIM][4];
  __shared__ float sWo[3][PDIM][8];
  __shared__ float sba[3][4];
  __shared__ float sbo[3][8];
  const int t = threadIdx.x;
  {
    float* wa = &sWa[0][0][0];
    for (int i = t; i < 144; i += 256) { wa[i] = Wa0[i]; wa[144 + i] = Wa1[i]; wa[288 + i] = Wa2[i]; }
    float* wo = &sWo[0][0][0];
    for (int i = t; i < 288; i += 256) { wo[i] = Wo0[i]; wo[288 + i] = Wo1[i]; wo[576 + i] = Wo2[i]; }
    if (t < 4) { sba[0][t] = ba0[t]; sba[1][t] = ba1[t]; sba[2][t] = ba2[t]; }
    if (t < 8) { sbo[0][t] = bo0[t]; sbo[1][t] = bo1[t]; sbo[2][t] = bo2[t]; }
  }
  __syncthreads();

  const int n = blockIdx.x * 256 + t;   // sorted position
  if (n >= NQ) return;
  const int q = (int)perm[n];

  float p[PDIM];
  const float4* pe4 = (const float4*)(pe + (size_t)q * PDIM);
#pragma unroll
  for (int i = 0; i < 9; ++i) {
    float4 v = pe4[i];
    p[4 * i + 0] = v.x; p[4 * i + 1] = v.y; p[4 * i + 2] = v.z; p[4 * i + 3] = v.w;
  }

  float la[3][4], of[3][8];
#pragma unroll
  for (int pl = 0; pl < 3; ++pl) {
#pragma unroll
    for (int k = 0; k < 4; ++k) la[pl][k] = sba[pl][k];
#pragma unroll
    for (int d = 0; d < 8; ++d) of[pl][d] = sbo[pl][d];
  }
#pragma unroll 4
  for (int j = 0; j < PDIM; ++j) {
    const float pj = p[j];
#pragma unroll
    for (int pl = 0; pl < 3; ++pl) {
#pragma unroll
      for (int k = 0; k < 4; ++k) la[pl][k] = fmaf(pj, sWa[pl][j][k], la[pl][k]);
#pragma unroll
      for (int d = 0; d < 8; ++d) of[pl][d] = fmaf(pj, sWo[pl][j][d], of[pl][d]);
    }
  }

  float* r = rec + (size_t)n * RECW;
  r[0] = query[q * 3 + 0];
  r[1] = query[q * 3 + 1];
  r[2] = query[q * 3 + 2];
  r[3] = __uint_as_float((unsigned int)q);
#pragma unroll
  for (int pl = 0; pl < 3; ++pl) {
    const float m = fmaxf(fmaxf(la[pl][0], la[pl][1]), fmaxf(la[pl][2], la[pl][3]));
    const float e0 = expf(la[pl][0] - m);
    const float e1 = expf(la[pl][1] - m);
    const float e2 = expf(la[pl][2] - m);
    const float e3 = expf(la[pl][3] - m);
    const float inv = 1.0f / (e0 + e1 + e2 + e3);
    r[4 + pl * 4 + 0] = e0 * inv;
    r[4 + pl * 4 + 1] = e1 * inv;
    r[4 + pl * 4 + 2] = e2 * inv;
    r[4 + pl * 4 + 3] = e3 * inv;
#pragma unroll
    for (int d = 0; d < 8; ++d) r[16 + pl * 8 + d] = of[pl][d];
  }
}

// ---- main gather: 1 wave per sorted query, lane = channel pair (2xbf16) ----
__global__ void sample_kernel(const float* __restrict__ rec,
                              const unsigned int* __restrict__ featT,
                              float* __restrict__ out) {
  const int lane = threadIdx.x & 63;
  const int wid = threadIdx.x >> 6;
  // bijective XCD chunk swizzle: 25000 blocks, 8 XCDs, 25000 % 8 == 0
  const int b = blockIdx.x;
  const int sb = (b & 7) * 3125 + (b >> 3);
  int i = sb * 4 + wid;
  i = __builtin_amdgcn_readfirstlane(i);
  if (i >= NQ) return;

  const float* __restrict__ r = rec + (size_t)i * RECW;
  const float qx = r[0];
  const float qy = r[1];
  const float qz = r[2];
  const int q = (int)__float_as_uint(r[3]);

  float at[12], of[24];
#pragma unroll
  for (int j = 0; j < 12; ++j) at[j] = r[4 + j];
#pragma unroll
  for (int j = 0; j < 24; ++j) of[j] = r[16 + j];

  float accx = 0.0f, accy = 0.0f;
#pragma unroll
  for (int pl = 0; pl < 3; ++pl) {
    // coords pair per plane: xy:(q0,q1) xz:(q0,q2) yz:(q1,q2)
    const float ca = (pl == 2) ? qy : qx;   // coords[...,0] -> gy
    const float cb = (pl == 0) ? qy : qz;   // coords[...,1] -> gx
    const unsigned int* __restrict__ f =
        featT + (size_t)pl * (size_t)HW * (CCH / 2) + lane;
#pragma unroll
    for (int k = 0; k < KPTS; ++k) {
      const float gy = ca + of[pl * 8 + k * 2 + 0];
      const float gx = cb + of[pl * 8 + k * 2 + 1];
      float x = ((gx + 1.0f) * (float)WDIM - 1.0f) * 0.5f;
      float y = ((gy + 1.0f) * (float)HDIM - 1.0f) * 0.5f;
      x = fminf(fmaxf(x, 0.0f), (float)(WDIM - 1));
      y = fminf(fmaxf(y, 0.0f), (float)(HDIM - 1));
      const float x0f = floorf(x), y0f = floorf(y);
      const float wx = x - x0f, wy = y - y0f;
      const int xi0 = (int)x0f, yi0 = (int)y0f;
      const int xi1 = min(xi0 + 1, WDIM - 1);
      const int yi1 = min(yi0 + 1, HDIM - 1);
      const float a = at[pl * 4 + k];
      const float w00 = a * (1.0f - wx) * (1.0f - wy);
      const float w01 = a * wx * (1.0f - wy);
      const float w10 = a * (1.0f - wx) * wy;
      const float w11 = a * wx * wy;
      const int r0 = (yi0 * WDIM) * (CCH / 2);
      const int r1 = (yi1 * WDIM) * (CCH / 2);
      const unsigned int u00 = f[r0 + xi0 * (CCH / 2)];
      const unsigned int u01 = f[r0 + xi1 * (CCH / 2)];
      const unsigned int u10 = f[r1 + xi0 * (CCH / 2)];
      const unsigned int u11 = f[r1 + xi1 * (CCH / 2)];
      // low 16 bits = even channel, high 16 bits = odd channel
      accx += w00 * __uint_as_float(u00 << 16) + w01 * __uint_as_float(u01 << 16) +
              w10 * __uint_as_float(u10 << 16) + w11 * __uint_as_float(u11 << 16);
      accy += w00 * __uint_as_float(u00 & 0xffff0000u) + w01 * __uint_as_float(u01 & 0xffff0000u) +
              w10 * __uint_as_float(u10 & 0xffff0000u) + w11 * __uint_as_float(u11 & 0xffff0000u);
    }
  }
  *(float2*)(out + (size_t)q * CCH + lane * 2) = make_float2(accx, accy);
}

// -------- fallback: fused, direct (C,H,W) gather (used only if ws too small) --------
__global__ void fused_fallback(const float* __restrict__ query,
                               const float* __restrict__ pe,
                               const float* __restrict__ f0,
                               const float* __restrict__ f1,
                               const float* __restrict__ f2,
                               const float* __restrict__ Wa0, const float* __restrict__ ba0,
                               const float* __restrict__ Wo0, const float* __restrict__ bo0,
                               const float* __restrict__ Wa1, const float* __restrict__ ba1,
                               const float* __restrict__ Wo1, const float* __restrict__ bo1,
                               const float* __restrict__ Wa2, const float* __restrict__ ba2,
                               const float* __restrict__ Wo2, const float* __restrict__ bo2,
                               float* __restrict__ out) {
  const int lane = threadIdx.x & 63;
  const int wid = threadIdx.x >> 6;
  int q = blockIdx.x * 4 + wid;
  q = __builtin_amdgcn_readfirstlane(q);
  if (q >= NQ) return;
  const float qx = query[q * 3 + 0];
  const float qy = query[q * 3 + 1];
  const float qz = query[q * 3 + 2];
  const float* pep = pe + (size_t)q * PDIM;
  const int c0i = lane * 2, c1i = lane * 2 + 1;
  float accx = 0.0f, accy = 0.0f;
#pragma unroll
  for (int pl = 0; pl < 3; ++pl) {
    const float* Wa = (pl == 0) ? Wa0 : ((pl == 1) ? Wa1 : Wa2);
    const float* ba = (pl == 0) ? ba0 : ((pl == 1) ? ba1 : ba2);
    const float* Wo = (pl == 0) ? Wo0 : ((pl == 1) ? Wo1 : Wo2);
    const float* bo = (pl == 0) ? bo0 : ((pl == 1) ? bo1 : bo2);
    const float* f = (pl == 0) ? f0 : ((pl == 1) ? f1 : f2);
    float la[4] = {ba[0], ba[1], ba[2], ba[3]};
    float of[8];
    for (int d = 0; d < 8; ++d) of[d] = bo[d];
    for (int j = 0; j < PDIM; ++j) {
      const float pj = pep[j];
      for (int k = 0; k < 4; ++k) la[k] = fmaf(pj, Wa[j * 4 + k], la[k]);
      for (int d = 0; d < 8; ++d) of[d] = fmaf(pj, Wo[j * 8 + d], of[d]);
    }
    const float m = fmaxf(fmaxf(la[0], la[1]), fmaxf(la[2], la[3]));
    float e[4], s = 0.0f;
    for (int k = 0; k < 4; ++k) { e[k] = expf(la[k] - m); s += e[k]; }
    const float inv = 1.0f / s;
    const float ca = (pl == 2) ? qy : qx;
    const float cb = (pl == 0) ? qy : qz;
    for (int k = 0; k < 4; ++k) {
      const float gy = ca + of[k * 2 + 0];
      const float gx = cb + of[k * 2 + 1];
      float x = ((gx + 1.0f) * (float)WDIM - 1.0f) * 0.5f;
      float y = ((gy + 1.0f) * (float)HDIM - 1.0f) * 0.5f;
      x = fminf(fmaxf(x, 0.0f), (float)(WDIM - 1));
      y = fminf(fmaxf(y, 0.0f), (float)(HDIM - 1));
      const float x0f = floorf(x), y0f = floorf(y);
      const float wx = x - x0f, wy = y - y0f;
      const int xi0 = (int)x0f, yi0 = (int)y0f;
      const int xi1 = min(xi0 + 1, WDIM - 1);
      const int yi1 = min(yi0 + 1, HDIM - 1);
      const float a = e[k] * inv;
      const float w00 = a * (1.0f - wx) * (1.0f - wy);
      const float w01 = a * wx * (1.0f - wy);
      const float w10 = a * (1.0f - wx) * wy;
      const float w11 = a * wx * wy;
      const size_t p00 = (size_t)(yi0 * WDIM + xi0);
      const size_t p01 = (size_t)(yi0 * WDIM + xi1);
      const size_t p10 = (size_t)(yi1 * WDIM + xi0);
      const size_t p11 = (size_t)(yi1 * WDIM + xi1);
      const float* fa = f + (size_t)c0i * HW;
      const float* fb = f + (size_t)c1i * HW;
      accx += w00 * fa[p00] + w01 * fa[p01] + w10 * fa[p10] + w11 * fa[p11];
      accy += w00 * fb[p00] + w01 * fb[p01] + w10 * fb[p10] + w11 * fb[p11];
    }
  }
  *(float2*)(out + (size_t)q * CCH + lane * 2) = make_float2(accx, accy);
}

extern "C" void kernel_launch(void* const* d_in, const int* in_sizes, int n_in,
                              void* d_out, int out_size, void* d_ws, size_t ws_size,
                              hipStream_t stream) {
  const float* query = (const float*)d_in[0];
  const float* pe    = (const float*)d_in[1];
  const float* feat0 = (const float*)d_in[2];
  const float* Wa0   = (const float*)d_in[3];
  const float* ba0   = (const float*)d_in[4];
  const float* Wo0   = (const float*)d_in[5];
  const float* bo0   = (const float*)d_in[6];
  const float* feat1 = (const float*)d_in[7];
  const float* Wa1   = (const float*)d_in[8];
  const float* ba1   = (const float*)d_in[9];
  const float* Wo1   = (const float*)d_in[10];
  const float* bo1   = (const float*)d_in[11];
  const float* feat2 = (const float*)d_in[12];
  const float* Wa2   = (const float*)d_in[13];
  const float* ba2   = (const float*)d_in[14];
  const float* Wo2   = (const float*)d_in[15];
  const float* bo2   = (const float*)d_in[16];
  float* out = (float*)d_out;

  const size_t featT_elems = 3ull * HW * (CCH / 2);  // uint32 count
  // layout: featT | rec (NQ*RECW f32) | counts | offs | perm
  const size_t need = featT_elems * 4 + (size_t)NQ * RECW * 4 +
                      (size_t)NBIN * 8 + (size_t)NQ * 4;

  if (ws_size >= need) {
    unsigned int* featT = (unsigned int*)d_ws;
    float* rec = (float*)(featT + featT_elems);
    unsigned int* counts = (unsigned int*)(rec + (size_t)NQ * RECW);
    unsigned int* offs = counts + NBIN;
    unsigned int* perm = offs + NBIN;

    zero_kernel<<<dim3((NBIN + 255) / 256), dim3(256), 0, stream>>>(counts);
    transpose_kernel<<<dim3(HW / 64, CCH / 64, 3), dim3(256), 0, stream>>>(
        feat0, feat1, feat2, featT);
    hist_kernel<<<dim3((NQ + 255) / 256), dim3(256), 0, stream>>>(query, counts);
    scan_kernel<<<dim3(1), dim3(1024), 0, stream>>>(counts, offs);
    scatter_kernel<<<dim3((NQ + 255) / 256), dim3(256), 0, stream>>>(query, offs, perm);
    weights_kernel<<<dim3((NQ + 255) / 256), dim3(256), 0, stream>>>(
        query, pe, perm, Wa0, ba0, Wo0, bo0, Wa1, ba1, Wo1, bo1,
        Wa2, ba2, Wo2, bo2, rec);
    sample_kernel<<<dim3(NQ / 4), dim3(256), 0, stream>>>(rec, featT, out);
  } else {
    fused_fallback<<<dim3((NQ + 3) / 4), dim3(256), 0, stream>>>(
        query, pe, feat0, feat1, feat2,
        Wa0, ba0, Wo0, bo0, Wa1, ba1, Wo1, bo1, Wa2, ba2, Wo2, bo2, out);
  }
}